// Round 9
// baseline (290.824 us; speedup 1.0000x reference)
//
#include <hip/hip_runtime.h>
#include <hip/hip_bf16.h>
#include <hip/hip_fp8.h>
#include <stdint.h>

#define NN 16384
#define DD 512
#define MARGINV 2.0f
#define EPSV 1e-6f

#define JGROUPS 8               // grid = 64 bi x 8 bj = 512 = 2 blocks/CU; bj == XCD (L2 locality)
#define JRANGE (NN / JGROUPS)   // 2048
#define NJT (JRANGE / 16)       // 128 16-j steps
#define RT_STRIDE 8192          // 16 rows x 512 B, fragment-ordered

#define KEYMASK  0xFFFFC000     // keep sign+exp+9 mantissa bits; low 14 = j (j<16384)
#define KEYINITF __builtin_bit_cast(float, 0x7F000000)   // big positive finite float
#define BIASV 640.0f            // > max sq_i: keys strictly positive, self provably rank 0

typedef __attribute__((ext_vector_type(4))) float f32x4;
typedef __attribute__((ext_vector_type(8))) int   i32x8;

#define UNIT_SCALE 0x7F   // E8M0 biased exponent 127 -> x1.0

// sorted-3 insert via med3 (keys are positive finite floats; float order == int order)
__device__ inline void kins3f(float u, float& m0, float& m1, float& m2) {
  m2 = __builtin_amdgcn_fmed3f(m1, m2, u);
  m1 = __builtin_amdgcn_fmed3f(m0, m1, u);
  m0 = fminf(m0, u);
}

// ---------------- Kernel 1: sq-norms (+BIASV) + fp8 quantize into MFMA-fragment layout ----
// Layout: rowtile RT (16 rows) x kchunk c (128): region at RT*8192 + c*2048, inside:
// [quadslot=(k%128)/32]*512 + [r16=row%16]*32 + [t=k%32]. A wave's (RT,c) fragment
// load is then base + lane*32 -- fully coalesced 2 KB.
extern "C" __global__ __launch_bounds__(256)
void prep_kernel(const float* __restrict__ x, unsigned char* __restrict__ xqB,
                 float* __restrict__ sqb, float* __restrict__ out) {
  if (blockIdx.x == 0 && threadIdx.x == 0) out[0] = 0.0f;   // replaces memset dispatch
  int row  = blockIdx.x * 4 + (threadIdx.x >> 6);
  int lane = threadIdx.x & 63;
  const float* xr = x + (size_t)row * DD + lane * 8;        // k = lane*8 .. +8
  f32x4 a = *(const f32x4*)xr;
  f32x4 b = *(const f32x4*)(xr + 4);
  float s = a[0]*a[0]+a[1]*a[1]+a[2]*a[2]+a[3]*a[3]
          + b[0]*b[0]+b[1]*b[1]+b[2]*b[2]+b[3]*b[3];
  #pragma unroll
  for (int off = 1; off < 64; off <<= 1) s += __shfl_xor(s, off, 64);
  unsigned long long pkv = 0;
  #pragma unroll
  for (int t = 0; t < 4; ++t) {
    __hip_fp8_e4m3 qa(a[t]), qb(b[t]);
    pkv |= ((unsigned long long)qa.__x) << (8 * t);
    pkv |= ((unsigned long long)qb.__x) << (8 * (t + 4));
  }
  // k = lane*8: c = lane>>4, quadslot = (lane&15)>>2, t0 = (lane&3)*8
  size_t dst = (size_t)(row >> 4) * RT_STRIDE + (lane >> 4) * 2048
             + ((lane & 15) >> 2) * 512 + (row & 15) * 32 + (lane & 3) * 8;
  *(unsigned long long*)(xqB + dst) = pkv;
  if (lane == 0) sqb[row] = s + BIASV;   // keys = sqb[j]-2dot > 0; self rank 0
}

// ---------------- Kernel 2: LDS-free streaming MX-fp8 GEMM + per-row packed top-3 --------
// No __shared__, no barriers. Each wave: 4 A-sets (64 i-rows, 128 regs) register-
// resident; B streams from L2 via coalesced dwordx4 pairs in fragment layout.
// Rolling 4-fragment prefetch: f[c] reloaded for jt+1 right after last use -> ~550 cyc
// prefetch distance >> L2 latency; compiler pipelines via vmcnt.
// mfma_scale 16x16x128 fp8 unit-scales (bit-identical to plain fp8, 2x rate).
extern "C" __global__ __launch_bounds__(256, 2)
void knn_kernel(const unsigned char* __restrict__ xqB, const float* __restrict__ sqb,
                int* __restrict__ pk) {
  const int tid  = threadIdx.x;
  const int wave = tid >> 6;
  const int lane = tid & 63;
  const int quad = lane >> 4;
  const int r16  = lane & 15;
  const int bi   = blockIdx.x >> 3;             // 0..63
  const int bj   = blockIdx.x & 7;              // 0..7 (== XCD under round-robin)
  const int ibase = bi * 256 + wave * 64;       // 64 i-rows per wave
  const int jbase = bj * JRANGE;
  const size_t laneoff = (size_t)lane * 32;

  // A fragments: 4 sets x 4 k-chunks, straight from fragment layout (coalesced)
  i32x8 afr[4][4];
  #pragma unroll
  for (int s = 0; s < 4; ++s) {
    const unsigned char* ab = xqB + (size_t)((ibase >> 4) + s) * RT_STRIDE + laneoff;
    #pragma unroll
    for (int c = 0; c < 4; ++c)
      afr[s][c] = *(const i32x8*)(ab + c * 2048);
  }

  // packed top-3 per (set s, reg r): q = s*4 + r; i-row = ibase + s*16 + quad*4 + r
  float m0[16], m1[16], m2[16];
  #pragma unroll
  for (int q = 0; q < 16; ++q) { m0[q] = m1[q] = m2[q] = KEYINITF; }

  const unsigned char* bbase = xqB + (size_t)(jbase >> 4) * RT_STRIDE + laneoff;

  // prime the 4-fragment rolling buffer with jt=0
  i32x8 f[4];
  #pragma unroll
  for (int c = 0; c < 4; ++c)
    f[c] = *(const i32x8*)(bbase + c * 2048);

  for (int jt = 0; jt < NJT; ++jt) {
    const unsigned char* bnext = bbase + (size_t)(jt + 1) * RT_STRIDE;  // last iter overreads 8KB into sqb region: harmless, unused
    f32x4 acc[4] = {{0.f,0.f,0.f,0.f},{0.f,0.f,0.f,0.f},
                    {0.f,0.f,0.f,0.f},{0.f,0.f,0.f,0.f}};
    #pragma unroll
    for (int c = 0; c < 4; ++c) {
      i32x8 bf = f[c];
      #pragma unroll
      for (int s = 0; s < 4; ++s)
        acc[s] = __builtin_amdgcn_mfma_scale_f32_16x16x128_f8f6f4(
                   afr[s][c], bf, acc[s], 0, 0, 0, UNIT_SCALE, 0, UNIT_SCALE);
      f[c] = *(const i32x8*)(bnext + c * 2048);          // prefetch jt+1 after last use
    }
    const int j = jbase + jt * 16 + r16;
    const float sqj = sqb[j];
    #pragma unroll
    for (int s = 0; s < 4; ++s) {
      #pragma unroll
      for (int r = 0; r < 4; ++r) {
        float v = fmaf(-2.0f, acc[s][r], sqj);           // > 0 by BIASV construction
        int   b = (__builtin_bit_cast(int, v) & KEYMASK) | j;   // v_and_or_b32
        kins3f(__builtin_bit_cast(float, b), m0[s*4+r], m1[s*4+r], m2[s*4+r]);
      }
    }
  }

  // ------- in-register butterfly merge across r16 (masks 1,2,4,8 stay in-quad) -------
  #pragma unroll
  for (int m = 1; m <= 8; m <<= 1) {
    #pragma unroll
    for (int q = 0; q < 16; ++q) {
      float o0 = __shfl_xor(m0[q], m, 64);
      float o1 = __shfl_xor(m1[q], m, 64);
      float o2 = __shfl_xor(m2[q], m, 64);
      kins3f(o0, m0[q], m1[q], m2[q]);
      kins3f(o1, m0[q], m1[q], m2[q]);
      kins3f(o2, m0[q], m1[q], m2[q]);
    }
  }

  // lane with r16 == q writes row q's merged packed top-3 (16 writers x 4 quads)
  #pragma unroll
  for (int q = 0; q < 16; ++q) {
    if (r16 == q) {
      int s  = q >> 2, r = q & 3;
      int gi = ibase + s * 16 + quad * 4 + r;
      int ob = (gi * JGROUPS + bj) * 3;
      pk[ob + 0] = __builtin_bit_cast(int, m0[q]);
      pk[ob + 1] = __builtin_bit_cast(int, m1[q]);
      pk[ob + 2] = __builtin_bit_cast(int, m2[q]);
    }
  }
}

// ---------------- Kernel 3: merge partials, fp32 norms, hinge, mean ----------------
extern "C" __global__ __launch_bounds__(256)
void finalize_kernel(const float* __restrict__ x, const float* __restrict__ pos,
                     const int* __restrict__ pk, float* __restrict__ out) {
  __shared__ float wsum[4];
  int i    = blockIdx.x * 4 + (threadIdx.x >> 6);
  int wave = threadIdx.x >> 6;
  int lane = threadIdx.x & 63;
  int neg = 0;
  if (lane == 0) {
    float m0 = KEYINITF, m1 = KEYINITF, m2 = KEYINITF;
    #pragma unroll
    for (int s = 0; s < JGROUPS * 3; ++s) {
      kins3f(__builtin_bit_cast(float, pk[i * (JGROUPS * 3) + s]), m0, m1, m2);
    }
    neg = __builtin_bit_cast(int, m2) & 0x3FFF;  // rank 2 (self rank 0) == idx3[:,2]
  }
  neg = __shfl(neg, 0, 64);
  const float* xr = x   + (size_t)i * DD + lane * 8;
  const float* pr = pos + (size_t)i * DD + lane * 8;
  const float* nr = x   + (size_t)neg * DD + lane * 8;
  f32x4 xa = *(const f32x4*)xr, xb4 = *(const f32x4*)(xr + 4);
  f32x4 pa = *(const f32x4*)pr, pb  = *(const f32x4*)(pr + 4);
  f32x4 na = *(const f32x4*)nr, nb  = *(const f32x4*)(nr + 4);
  float sap = 0.f, san = 0.f;
  #pragma unroll
  for (int k = 0; k < 4; ++k) {
    float d0 = xa[k]  - pa[k] + EPSV; sap = fmaf(d0, d0, sap);
    float d1 = xa[k]  - na[k] + EPSV; san = fmaf(d1, d1, san);
    float d2 = xb4[k] - pb[k] + EPSV; sap = fmaf(d2, d2, sap);
    float d3 = xb4[k] - nb[k] + EPSV; san = fmaf(d3, d3, san);
  }
  #pragma unroll
  for (int off = 1; off < 64; off <<= 1) {
    sap += __shfl_xor(sap, off, 64);
    san += __shfl_xor(san, off, 64);
  }
  if (lane == 0) {
    float l = sqrtf(sap) - sqrtf(san) + MARGINV;
    wsum[wave] = l > 0.f ? l : 0.f;
  }
  __syncthreads();
  if (threadIdx.x == 0) {
    atomicAdd(out, (wsum[0] + wsum[1] + wsum[2] + wsum[3]) * (1.0f / NN));
  }
}

// ---------------- host ----------------
extern "C" void kernel_launch(void* const* d_in, const int* in_sizes, int n_in,
                              void* d_out, int out_size, void* d_ws, size_t ws_size,
                              hipStream_t stream) {
  const float* x   = (const float*)d_in[0];
  const float* pos = (const float*)d_in[1];
  char* ws = (char*)d_ws;
  unsigned char* xqB = (unsigned char*)ws;                                // 8 MB (fragment layout)
  float* sqb = (float*)(ws + (size_t)NN * 512);                           // 64 KB
  int*   pk  = (int*)  (ws + (size_t)NN * 512 + (size_t)NN * 4);          // 1.5 MB

  prep_kernel<<<NN / 4, 256, 0, stream>>>(x, xqB, sqb, (float*)d_out);
  knn_kernel<<<(NN / 256) * JGROUPS, 256, 0, stream>>>(xqB, sqb, pk);
  finalize_kernel<<<NN / 4, 256, 0, stream>>>(x, pos, pk, (float*)d_out);
}